// Round 2
// baseline (187.453 us; speedup 1.0000x reference)
//
#include <hip/hip_runtime.h>
#include <hip/hip_bf16.h>

typedef __attribute__((ext_vector_type(4))) float f32x4;
typedef __attribute__((ext_vector_type(8))) short bf16x8;

#define NROWS 32768
#define DIM   2048
#define NEXP  64

__device__ __forceinline__ short f2bf(float f) {
    __hip_bfloat16 h = __float2bfloat16(f);   // RTNE
    short s;
    __builtin_memcpy(&s, &h, 2);
    return s;
}

// ---------------- Kernel A: expert prep -------------------------------------
__global__ __launch_bounds__(256) void prep_experts(
    const float* __restrict__ ek,
    short* __restrict__ ekbf,
    short* __restrict__ ekT,
    float* __restrict__ enorm)
{
    const int e = blockIdx.x;      // expert 0..63
    const int t = threadIdx.x;     // 0..255
    const float* row = ek + e * DIM;
    float ss = 0.f;
#pragma unroll
    for (int i = 0; i < 2; ++i) {
        const int c4 = t + i * 256;              // float4 index 0..511
        const float4 v = ((const float4*)row)[c4];
        ss += v.x * v.x + v.y * v.y + v.z * v.z + v.w * v.w;
        short4 b;
        b.x = f2bf(v.x); b.y = f2bf(v.y); b.z = f2bf(v.z); b.w = f2bf(v.w);
        *(short4*)(ekbf + e * DIM + c4 * 4) = b;
        const int d = c4 * 4;
        ekT[(d + 0) * NEXP + e] = b.x;
        ekT[(d + 1) * NEXP + e] = b.y;
        ekT[(d + 2) * NEXP + e] = b.z;
        ekT[(d + 3) * NEXP + e] = b.w;
    }
#pragma unroll
    for (int s = 1; s < 64; s <<= 1) ss += __shfl_xor(ss, s);
    __shared__ float red[4];
    if ((t & 63) == 0) red[t >> 6] = ss;
    __syncthreads();
    if (t == 0) enorm[e] = sqrtf(red[0] + red[1] + red[2] + red[3]);
}

// ---------------- Main kernel ------------------------------------------------
// 32 rows per block, 4 waves. Phase 1: wave pair (p = w>>1) owns m-tile p
// (16 rows); the two waves of a pair split K=2048 in half (s = w&1).
// Partials reduced via LDS. Phase 3: each wave owns a 512-wide d-slice.
__global__ __launch_bounds__(256) void cosmoe_main(
    const float* __restrict__ z,
    const short* __restrict__ ekbf,   // [64][2048] bf16
    const short* __restrict__ ekT,    // [2048][64] bf16
    const float* __restrict__ enorm,  // [64] f32
    float* __restrict__ out_sim,      // [32768][64] f32
    float* __restrict__ out_wei)      // [32768][2048] f32
{
    const int tid = threadIdx.x;
    const int w   = tid >> 6;     // wave 0..3
    const int l   = tid & 63;
    const int lr  = l & 15;       // A-row / B-col / C-col within 16-tile
    const int lg  = l >> 4;       // k-group 0..3
    const int p   = w >> 1;       // m-tile (0,1)
    const int s   = w & 1;        // K-half
    const int base_row = blockIdx.x * 32;

    __shared__ float racc[2][64][17];          // partner partial acc (padded)
    __shared__ float rssq[2][16];
    __shared__ __align__(16) short Wl[2][16][72];

    // ---- Phase 1: dots (split-K) + f32 sum-of-squares (4 independent chains)
    const float* zrow = z + (size_t)(base_row + p * 16 + lr) * DIM + s * 1024 + lg * 8;
    f32x4 acc[4];
#pragma unroll
    for (int nt = 0; nt < 4; ++nt) acc[nt] = f32x4{0.f, 0.f, 0.f, 0.f};
    float ss0 = 0.f, ss1 = 0.f, ss2 = 0.f, ss3 = 0.f;

    for (int kk = 0; kk < 32; kk += 4) {
        float4 v[8];
#pragma unroll
        for (int u = 0; u < 4; ++u) {
            v[2 * u]     = *(const float4*)(zrow + (kk + u) * 32);
            v[2 * u + 1] = *(const float4*)(zrow + (kk + u) * 32 + 4);
        }
#pragma unroll
        for (int u = 0; u < 4; ++u) {
            const float4 a0 = v[2 * u], a1 = v[2 * u + 1];
            ss0 = fmaf(a0.x, a0.x, ss0); ss1 = fmaf(a0.y, a0.y, ss1);
            ss2 = fmaf(a0.z, a0.z, ss2); ss3 = fmaf(a0.w, a0.w, ss3);
            ss0 = fmaf(a1.x, a1.x, ss0); ss1 = fmaf(a1.y, a1.y, ss1);
            ss2 = fmaf(a1.z, a1.z, ss2); ss3 = fmaf(a1.w, a1.w, ss3);
            bf16x8 af;
            af[0] = f2bf(a0.x); af[1] = f2bf(a0.y); af[2] = f2bf(a0.z); af[3] = f2bf(a0.w);
            af[4] = f2bf(a1.x); af[5] = f2bf(a1.y); af[6] = f2bf(a1.z); af[7] = f2bf(a1.w);
            const int koff = s * 1024 + (kk + u) * 32 + lg * 8;
#pragma unroll
            for (int nt = 0; nt < 4; ++nt) {
                const bf16x8 bf = *(const bf16x8*)(ekbf + (nt * 16 + lr) * DIM + koff);
                acc[nt] = __builtin_amdgcn_mfma_f32_16x16x32_bf16(af, bf, acc[nt], 0, 0, 0);
            }
        }
    }
    float ssq = (ss0 + ss1) + (ss2 + ss3);
    // combine the 4 k-groups within the wave (rows repeat every 16 lanes):
    ssq += __shfl_xor(ssq, 16);
    ssq += __shfl_xor(ssq, 32);

    // ---- cross-wave (split-K) reduction through LDS
    if (s == 1) {
#pragma unroll
        for (int nt = 0; nt < 4; ++nt)
#pragma unroll
            for (int j = 0; j < 4; ++j) racc[p][l][nt * 4 + j] = acc[nt][j];
        if (l < 16) rssq[p][l] = ssq;
    }
    __syncthreads();

    if (s == 0) {
#pragma unroll
        for (int nt = 0; nt < 4; ++nt)
#pragma unroll
            for (int j = 0; j < 4; ++j) acc[nt][j] += racc[p][l][nt * 4 + j];
        ssq += rssq[p][lr];
        const float zn_mine = sqrtf(ssq);  // ||z[base+p*16+lr]||

        // ---- Phase 2: similarity + softmax (C layout: lane holds D[lg*4+j][lr])
        float zn_j[4];
#pragma unroll
        for (int j = 0; j < 4; ++j) zn_j[j] = __shfl(zn_mine, lg * 4 + j);
        float en_nt[4];
#pragma unroll
        for (int nt = 0; nt < 4; ++nt) en_nt[nt] = enorm[nt * 16 + lr];

        float sim[4][4];   // [nt][j]
#pragma unroll
        for (int j = 0; j < 4; ++j)
#pragma unroll
            for (int nt = 0; nt < 4; ++nt)
                sim[nt][j] = acc[nt][j] / fmaxf(zn_j[j] * en_nt[nt], 1e-8f);

#pragma unroll
        for (int j = 0; j < 4; ++j) {
            const size_t ro = (size_t)(base_row + p * 16 + lg * 4 + j) * NEXP + lr;
#pragma unroll
            for (int nt = 0; nt < 4; ++nt) out_sim[ro + nt * 16] = sim[nt][j];
        }

        float wgt[4][4];
#pragma unroll
        for (int j = 0; j < 4; ++j) {
            float mx = fmaxf(fmaxf(sim[0][j], sim[1][j]), fmaxf(sim[2][j], sim[3][j]));
#pragma unroll
            for (int t = 1; t < 16; t <<= 1) mx = fmaxf(mx, __shfl_xor(mx, t));
            float sum = 0.f;
#pragma unroll
            for (int nt = 0; nt < 4; ++nt) { wgt[nt][j] = __expf(sim[nt][j] - mx); sum += wgt[nt][j]; }
#pragma unroll
            for (int t = 1; t < 16; t <<= 1) sum += __shfl_xor(sum, t);
            const float inv = 1.0f / sum;
#pragma unroll
            for (int nt = 0; nt < 4; ++nt) wgt[nt][j] *= inv;
        }

#pragma unroll
        for (int j = 0; j < 4; ++j)
#pragma unroll
            for (int nt = 0; nt < 4; ++nt)
                Wl[p][lg * 4 + j][nt * 16 + lr] = f2bf(wgt[nt][j]);
    }
    __syncthreads();

    // ---- Phase 3: weighted = W[32x64] @ ek[64x2048]; wave w owns d-slice w*512
    bf16x8 afr[2][2];
#pragma unroll
    for (int mt = 0; mt < 2; ++mt)
#pragma unroll
        for (int ks = 0; ks < 2; ++ks)
            afr[mt][ks] = *(const bf16x8*)&Wl[mt][lr][ks * 32 + lg * 8];

#pragma unroll 2
    for (int ntl = 0; ntl < 32; ++ntl) {
        const int d0 = w * 512 + ntl * 16;
        const short* bp = ekT + (size_t)(d0 + lr) * NEXP + lg * 8;
        const bf16x8 b0 = *(const bf16x8*)bp;          // experts 0..31 slice
        const bf16x8 b1 = *(const bf16x8*)(bp + 32);   // experts 32..63 slice
        f32x4 oacc[2];
#pragma unroll
        for (int mt = 0; mt < 2; ++mt) {
            oacc[mt] = f32x4{0.f, 0.f, 0.f, 0.f};
            oacc[mt] = __builtin_amdgcn_mfma_f32_16x16x32_bf16(afr[mt][0], b0, oacc[mt], 0, 0, 0);
            oacc[mt] = __builtin_amdgcn_mfma_f32_16x16x32_bf16(afr[mt][1], b1, oacc[mt], 0, 0, 0);
        }
#pragma unroll
        for (int mt = 0; mt < 2; ++mt)
#pragma unroll
            for (int j = 0; j < 4; ++j)
                out_wei[(size_t)(base_row + mt * 16 + lg * 4 + j) * DIM + d0 + lr] = oacc[mt][j];
    }
}

// ---------------- launch -----------------------------------------------------
extern "C" void kernel_launch(void* const* d_in, const int* in_sizes, int n_in,
                              void* d_out, int out_size, void* d_ws, size_t ws_size,
                              hipStream_t stream) {
    const float* z  = (const float*)d_in[0];
    const float* ek = (const float*)d_in[1];
    float* out_sim = (float*)d_out;
    float* out_wei = out_sim + (size_t)NROWS * NEXP;

    short* ekbf  = (short*)d_ws;                 // 64*2048*2   = 256 KiB
    short* ekT   = ekbf + NEXP * DIM;            // 2048*64*2   = 256 KiB
    float* enorm = (float*)(ekT + DIM * NEXP);   // 64*4 bytes

    prep_experts<<<NEXP, 256, 0, stream>>>(ek, ekbf, ekT, enorm);
    cosmoe_main<<<NROWS / 32, 256, 0, stream>>>(z, ekbf, ekT, enorm, out_sim, out_wei);
}

// Round 3
// 177.202 us; speedup vs baseline: 1.0578x; 1.0578x over previous
//
#include <hip/hip_runtime.h>
#include <hip/hip_bf16.h>

typedef __attribute__((ext_vector_type(4))) float f32x4;
typedef __attribute__((ext_vector_type(8))) short bf16x8;

#define NROWS 32768
#define DIM   2048
#define NEXP  64

__device__ __forceinline__ short f2bf(float f) {
    __hip_bfloat16 h = __float2bfloat16(f);   // RTNE
    short s;
    __builtin_memcpy(&s, &h, 2);
    return s;
}

// ---------------- Kernel A: expert prep -------------------------------------
__global__ __launch_bounds__(256) void prep_experts(
    const float* __restrict__ ek,
    short* __restrict__ ekbf,
    short* __restrict__ ekT,
    float* __restrict__ enorm)
{
    const int e = blockIdx.x;      // expert 0..63
    const int t = threadIdx.x;     // 0..255
    const float* row = ek + e * DIM;
    float ss = 0.f;
#pragma unroll
    for (int i = 0; i < 2; ++i) {
        const int c4 = t + i * 256;              // float4 index 0..511
        const float4 v = ((const float4*)row)[c4];
        ss += v.x * v.x + v.y * v.y + v.z * v.z + v.w * v.w;
        short4 b;
        b.x = f2bf(v.x); b.y = f2bf(v.y); b.z = f2bf(v.z); b.w = f2bf(v.w);
        *(short4*)(ekbf + e * DIM + c4 * 4) = b;
        const int d = c4 * 4;
        ekT[(d + 0) * NEXP + e] = b.x;
        ekT[(d + 1) * NEXP + e] = b.y;
        ekT[(d + 2) * NEXP + e] = b.z;
        ekT[(d + 3) * NEXP + e] = b.w;
    }
#pragma unroll
    for (int s = 1; s < 64; s <<= 1) ss += __shfl_xor(ss, s);
    __shared__ float red[4];
    if ((t & 63) == 0) red[t >> 6] = ss;
    __syncthreads();
    if (t == 0) enorm[e] = sqrtf(red[0] + red[1] + red[2] + red[3]);
}

// ---------------- Main kernel ------------------------------------------------
// 64 rows per block, 4 waves, wave w owns m-tile w (phase 1) and d-slice w*512
// (phase 3). Deep register prefetch: depth-4 (phase 1), depth-2 (phase 3).

struct P1Buf { float4 z0, z1; bf16x8 e0, e1, e2, e3; };

__device__ __forceinline__ void p1_load(P1Buf& b, const float* zrow,
                                        const short* ekbf, int lr, int lg, int kk) {
    b.z0 = *(const float4*)(zrow + kk * 32);
    b.z1 = *(const float4*)(zrow + kk * 32 + 4);
    const int koff = kk * 32 + lg * 8;
    b.e0 = *(const bf16x8*)(ekbf + (0 * 16 + lr) * DIM + koff);
    b.e1 = *(const bf16x8*)(ekbf + (1 * 16 + lr) * DIM + koff);
    b.e2 = *(const bf16x8*)(ekbf + (2 * 16 + lr) * DIM + koff);
    b.e3 = *(const bf16x8*)(ekbf + (3 * 16 + lr) * DIM + koff);
}

__device__ __forceinline__ void p1_compute(const P1Buf& b, f32x4 acc[4],
        float& s0, float& s1, float& s2, float& s3) {
    const float4 a0 = b.z0, a1 = b.z1;
    s0 = fmaf(a0.x, a0.x, s0); s1 = fmaf(a0.y, a0.y, s1);
    s2 = fmaf(a0.z, a0.z, s2); s3 = fmaf(a0.w, a0.w, s3);
    s0 = fmaf(a1.x, a1.x, s0); s1 = fmaf(a1.y, a1.y, s1);
    s2 = fmaf(a1.z, a1.z, s2); s3 = fmaf(a1.w, a1.w, s3);
    bf16x8 af;
    af[0] = f2bf(a0.x); af[1] = f2bf(a0.y); af[2] = f2bf(a0.z); af[3] = f2bf(a0.w);
    af[4] = f2bf(a1.x); af[5] = f2bf(a1.y); af[6] = f2bf(a1.z); af[7] = f2bf(a1.w);
    acc[0] = __builtin_amdgcn_mfma_f32_16x16x32_bf16(af, b.e0, acc[0], 0, 0, 0);
    acc[1] = __builtin_amdgcn_mfma_f32_16x16x32_bf16(af, b.e1, acc[1], 0, 0, 0);
    acc[2] = __builtin_amdgcn_mfma_f32_16x16x32_bf16(af, b.e2, acc[2], 0, 0, 0);
    acc[3] = __builtin_amdgcn_mfma_f32_16x16x32_bf16(af, b.e3, acc[3], 0, 0, 0);
}

struct P3Buf { bf16x8 b0, b1; };

__device__ __forceinline__ void p3_load(P3Buf& b, const short* ekT,
                                        int w, int lr, int lg, int ntl) {
    const int d0 = w * 512 + ntl * 16;
    const short* bp = ekT + (size_t)(d0 + lr) * NEXP + lg * 8;
    b.b0 = *(const bf16x8*)bp;
    b.b1 = *(const bf16x8*)(bp + 32);
}

__global__ __launch_bounds__(256, 2) void cosmoe_main(
    const float* __restrict__ z,
    const short* __restrict__ ekbf,   // [64][2048] bf16
    const short* __restrict__ ekT,    // [2048][64] bf16
    const float* __restrict__ enorm,  // [64] f32
    float* __restrict__ out_sim,      // [32768][64] f32
    float* __restrict__ out_wei)      // [32768][2048] f32
{
    const int tid = threadIdx.x;
    const int w   = tid >> 6;     // wave 0..3
    const int l   = tid & 63;
    const int lr  = l & 15;       // A-row / B-col / C-col within 16-tile
    const int lg  = l >> 4;       // k-group 0..3
    const int base_row = blockIdx.x * 64;

    // ---- Phase 1: dots = z @ ek^T for 64 rows; f32 z-norms on the side.
    const float* zrow = z + (size_t)(base_row + w * 16 + lr) * DIM + lg * 8;
    f32x4 acc[4];
#pragma unroll
    for (int nt = 0; nt < 4; ++nt) acc[nt] = f32x4{0.f, 0.f, 0.f, 0.f};
    float ss0 = 0.f, ss1 = 0.f, ss2 = 0.f, ss3 = 0.f;

    P1Buf A, B, C, D;
    p1_load(A, zrow, ekbf, lr, lg, 0);
    p1_load(B, zrow, ekbf, lr, lg, 1);
    p1_load(C, zrow, ekbf, lr, lg, 2);
    p1_load(D, zrow, ekbf, lr, lg, 3);

    for (int kk = 0; kk < 64; kk += 4) {
        p1_compute(A, acc, ss0, ss1, ss2, ss3);
        if (kk < 60) p1_load(A, zrow, ekbf, lr, lg, kk + 4);
        p1_compute(B, acc, ss0, ss1, ss2, ss3);
        if (kk < 60) p1_load(B, zrow, ekbf, lr, lg, kk + 5);
        p1_compute(C, acc, ss0, ss1, ss2, ss3);
        if (kk < 60) p1_load(C, zrow, ekbf, lr, lg, kk + 6);
        p1_compute(D, acc, ss0, ss1, ss2, ss3);
        if (kk < 60) p1_load(D, zrow, ekbf, lr, lg, kk + 7);
    }

    float ssq = (ss0 + ss1) + (ss2 + ss3);
    ssq += __shfl_xor(ssq, 16);
    ssq += __shfl_xor(ssq, 32);
    const float zn_mine = sqrtf(ssq);   // ||z[w*16+lr]||

    // ---- Phase 2: similarity + softmax over 64 experts.
    // C layout: lane holds D[lg*4+j][lr] per n-tile (verified R1: passed).
    float zn_j[4];
#pragma unroll
    for (int j = 0; j < 4; ++j) zn_j[j] = __shfl(zn_mine, lg * 4 + j);
    float en_nt[4];
#pragma unroll
    for (int nt = 0; nt < 4; ++nt) en_nt[nt] = enorm[nt * 16 + lr];

    float sim[4][4];   // [nt][j]
#pragma unroll
    for (int j = 0; j < 4; ++j)
#pragma unroll
        for (int nt = 0; nt < 4; ++nt)
            sim[nt][j] = acc[nt][j] / fmaxf(zn_j[j] * en_nt[nt], 1e-8f);

#pragma unroll
    for (int j = 0; j < 4; ++j) {
        const size_t ro = (size_t)(base_row + w * 16 + lg * 4 + j) * NEXP + lr;
#pragma unroll
        for (int nt = 0; nt < 4; ++nt)
            __builtin_nontemporal_store(sim[nt][j], &out_sim[ro + nt * 16]);
    }

    float wgt[4][4];
#pragma unroll
    for (int j = 0; j < 4; ++j) {
        float mx = fmaxf(fmaxf(sim[0][j], sim[1][j]), fmaxf(sim[2][j], sim[3][j]));
#pragma unroll
        for (int t = 1; t < 16; t <<= 1) mx = fmaxf(mx, __shfl_xor(mx, t));
        float sum = 0.f;
#pragma unroll
        for (int nt = 0; nt < 4; ++nt) { wgt[nt][j] = __expf(sim[nt][j] - mx); sum += wgt[nt][j]; }
#pragma unroll
        for (int t = 1; t < 16; t <<= 1) sum += __shfl_xor(sum, t);
        const float inv = 1.0f / sum;
#pragma unroll
        for (int nt = 0; nt < 4; ++nt) wgt[nt][j] *= inv;
    }

    // re-layout W: C-frag -> A-frag via small padded LDS tile (stride 72 => 2-way max)
    __shared__ __align__(16) short Wl[4][16][72];
#pragma unroll
    for (int j = 0; j < 4; ++j)
#pragma unroll
        for (int nt = 0; nt < 4; ++nt)
            Wl[w][lg * 4 + j][nt * 16 + lr] = f2bf(wgt[nt][j]);
    __syncthreads();

    // ---- Phase 3: weighted = W[64x64] @ ek[64x2048]; wave w owns d-slice w*512
    bf16x8 afr[4][2];
#pragma unroll
    for (int mt = 0; mt < 4; ++mt)
#pragma unroll
        for (int ks = 0; ks < 2; ++ks)
            afr[mt][ks] = *(const bf16x8*)&Wl[mt][lr][ks * 32 + lg * 8];

    P3Buf PA, PB;
    p3_load(PA, ekT, w, lr, lg, 0);
    p3_load(PB, ekT, w, lr, lg, 1);

    for (int base = 0; base < 32; base += 2) {
        {
            const int d0 = w * 512 + base * 16;
            f32x4 oacc[4];
#pragma unroll
            for (int mt = 0; mt < 4; ++mt) {
                oacc[mt] = f32x4{0.f, 0.f, 0.f, 0.f};
                oacc[mt] = __builtin_amdgcn_mfma_f32_16x16x32_bf16(afr[mt][0], PA.b0, oacc[mt], 0, 0, 0);
                oacc[mt] = __builtin_amdgcn_mfma_f32_16x16x32_bf16(afr[mt][1], PA.b1, oacc[mt], 0, 0, 0);
            }
            if (base < 30) p3_load(PA, ekT, w, lr, lg, base + 2);
#pragma unroll
            for (int mt = 0; mt < 4; ++mt)
#pragma unroll
                for (int j = 0; j < 4; ++j)
                    __builtin_nontemporal_store(oacc[mt][j],
                        &out_wei[(size_t)(base_row + mt * 16 + lg * 4 + j) * DIM + d0 + lr]);
        }
        {
            const int d0 = w * 512 + (base + 1) * 16;
            f32x4 oacc[4];
#pragma unroll
            for (int mt = 0; mt < 4; ++mt) {
                oacc[mt] = f32x4{0.f, 0.f, 0.f, 0.f};
                oacc[mt] = __builtin_amdgcn_mfma_f32_16x16x32_bf16(afr[mt][0], PB.b0, oacc[mt], 0, 0, 0);
                oacc[mt] = __builtin_amdgcn_mfma_f32_16x16x32_bf16(afr[mt][1], PB.b1, oacc[mt], 0, 0, 0);
            }
            if (base < 30) p3_load(PB, ekT, w, lr, lg, base + 3);
#pragma unroll
            for (int mt = 0; mt < 4; ++mt)
#pragma unroll
                for (int j = 0; j < 4; ++j)
                    __builtin_nontemporal_store(oacc[mt][j],
                        &out_wei[(size_t)(base_row + mt * 16 + lg * 4 + j) * DIM + d0 + lr]);
        }
    }
}

// ---------------- launch -----------------------------------------------------
extern "C" void kernel_launch(void* const* d_in, const int* in_sizes, int n_in,
                              void* d_out, int out_size, void* d_ws, size_t ws_size,
                              hipStream_t stream) {
    const float* z  = (const float*)d_in[0];
    const float* ek = (const float*)d_in[1];
    float* out_sim = (float*)d_out;
    float* out_wei = out_sim + (size_t)NROWS * NEXP;

    short* ekbf  = (short*)d_ws;                 // 64*2048*2   = 256 KiB
    short* ekT   = ekbf + NEXP * DIM;            // 2048*64*2   = 256 KiB
    float* enorm = (float*)(ekT + DIM * NEXP);   // 64*4 bytes

    prep_experts<<<NEXP, 256, 0, stream>>>(ek, ekbf, ekT, enorm);
    cosmoe_main<<<NROWS / 64, 256, 0, stream>>>(z, ekbf, ekT, enorm, out_sim, out_wei);
}